// Round 4
// baseline (902.460 us; speedup 1.0000x reference)
//
#include <hip/hip_runtime.h>
#include <math.h>

#define N_NODESC 50000
#define N_EDGESC 800000
#define N_GRAPHSC 64
#define IN_DIMC 128
#define HIDC 256
#define N_LAYERSC 4
#define EPSV 1e-12f

#define SCAN_BLK 196  // ceil(50000/256)

typedef __attribute__((ext_vector_type(8))) short short8;
typedef __attribute__((ext_vector_type(4))) float floatx4;

__device__ __forceinline__ unsigned short f2b(float f) {
    union { float f; unsigned u; } v; v.f = f;
    unsigned r = v.u + 0x7FFFu + ((v.u >> 16) & 1u);
    return (unsigned short)(r >> 16);
}
__device__ __forceinline__ float blo(unsigned u) { return __uint_as_float(u << 16); }
__device__ __forceinline__ float bhi(unsigned u) { return __uint_as_float(u & 0xFFFF0000u); }
__device__ __forceinline__ unsigned pkb(float a, float b) {
    return (unsigned)f2b(a) | ((unsigned)f2b(b) << 16);
}
__device__ __forceinline__ float b2f(unsigned short s) {
    return __uint_as_float((unsigned)s << 16);
}

// ---------------- degree count ----------------
__global__ void k_count(const int* __restrict__ dst, int* __restrict__ deg) {
    int e = blockIdx.x * blockDim.x + threadIdx.x;
    if (e < N_EDGESC) atomicAdd(&deg[dst[e]], 1);
}

// ---------------- graph histogram ----------------
__global__ void k_gcount(const int* __restrict__ gid, int* __restrict__ gdeg) {
    int i = blockIdx.x * blockDim.x + threadIdx.x;
    if (i < N_NODESC) atomicAdd(&gdeg[gid[i]], 1);
}

// ---------------- graph prefix (64 graphs, 1 block) ----------------
__global__ __launch_bounds__(64) void k_gprefix(const int* __restrict__ gdeg,
        int* __restrict__ gstart) {
    __shared__ int s[64];
    int t = threadIdx.x;
    int v = gdeg[t];
    s[t] = v;
    __syncthreads();
    for (int d = 1; d < 64; d <<= 1) {
        int u = (t >= d) ? s[t - d] : 0;
        __syncthreads();
        s[t] += u;
        __syncthreads();
    }
    gstart[t] = s[t] - v;
    if (t == 63) gstart[64] = s[63];
}

// ---------------- hierarchical scan: A = block sums ----------------
__global__ __launch_bounds__(256) void k_scanA(const int* __restrict__ deg,
        int* __restrict__ bsum) {
    __shared__ int s[256];
    int t = threadIdx.x;
    int i = blockIdx.x * 256 + t;
    s[t] = (i < N_NODESC) ? deg[i] : 0;
    __syncthreads();
    for (int d = 128; d > 0; d >>= 1) {
        if (t < d) s[t] += s[t + d];
        __syncthreads();
    }
    if (t == 0) bsum[blockIdx.x] = s[0];
}

// ---------------- B = exclusive scan of block sums ----------------
__global__ __launch_bounds__(256) void k_scanB(const int* __restrict__ bsum,
        int* __restrict__ boff) {
    __shared__ int s[256];
    int t = threadIdx.x;
    int v = (t < SCAN_BLK) ? bsum[t] : 0;
    s[t] = v;
    __syncthreads();
    for (int d = 1; d < 256; d <<= 1) {
        int u = (t >= d) ? s[t - d] : 0;
        __syncthreads();
        s[t] += u;
        __syncthreads();
    }
    if (t < SCAN_BLK) boff[t] = s[t] - v;
}

// ---------------- C = per-block exclusive scan + base ----------------
__global__ __launch_bounds__(256) void k_scanC(const int* __restrict__ deg,
        const int* __restrict__ boff, int* __restrict__ offs, int* __restrict__ cursor) {
    __shared__ int s[256];
    int t = threadIdx.x;
    int i = blockIdx.x * 256 + t;
    int v = (i < N_NODESC) ? deg[i] : 0;
    s[t] = v;
    __syncthreads();
    for (int d = 1; d < 256; d <<= 1) {
        int u = (t >= d) ? s[t - d] : 0;
        __syncthreads();
        s[t] += u;
        __syncthreads();
    }
    int excl = s[t] - v + boff[blockIdx.x];
    if (i < N_NODESC) {
        offs[i] = excl;
        cursor[i] = excl;
        if (i == N_NODESC - 1) offs[N_NODESC] = excl + v;
    }
}

// ---------------- scatter edges into CSR buckets ----------------
__global__ void k_scatter(const int* __restrict__ src, const int* __restrict__ dst,
        int* __restrict__ cursor, int* __restrict__ esrc) {
    int e = blockIdx.x * blockDim.x + threadIdx.x;
    if (e < N_EDGESC) {
        int d = dst[e];
        int pos = atomicAdd(&cursor[d], 1);
        esrc[pos] = src[e];
    }
}

// ---------------- weight convert + swizzle to MFMA B-fragment order ----------------
__global__ __launch_bounds__(256) void k_wconv(const float* __restrict__ Wemb,
        const float* __restrict__ Ws, unsigned short* __restrict__ wsw) {
    int idx = blockIdx.x * 256 + threadIdx.x;
    const int EMB = IN_DIMC * HIDC;           // 32768
    const int LYR = 2 * HIDC * HIDC;          // 131072
    if (idx >= EMB + N_LAYERSC * LYR) return;
    float val; int k, n; unsigned short* basep;
    if (idx < EMB) {
        k = idx >> 8; n = idx & 255;
        val = Wemb[idx];
        basep = wsw;
    } else {
        int r = idx - EMB;
        int l = r >> 17;
        int r2 = r & (LYR - 1);
        k = r2 >> 8; n = r2 & 255;
        val = Ws[r];
        basep = wsw + EMB + l * LYR;
    }
    int off = (((k >> 5) * 16 + (n >> 4)) * 64 + ((((k >> 3) & 3) << 4) | (n & 15))) * 8 + (k & 7);
    basep[off] = f2b(val);
}

// ---------------- per-node mean aggregation (32 lanes/node, uint4/lane, 8-deep MLP) ----------------
__global__ __launch_bounds__(256) void k_aggregate(const unsigned short* __restrict__ xb,
        const int* __restrict__ offs, const int* __restrict__ esrc,
        unsigned short* __restrict__ cb) {
    int gidx = blockIdx.x * 256 + threadIdx.x;
    int node = gidx >> 5;
    int lane = threadIdx.x & 31;
    if (node >= N_NODESC) return;
    int beg = offs[node], end = offs[node + 1];
    float a[8];
    #pragma unroll
    for (int j = 0; j < 8; j++) a[j] = 0.f;
    size_t loff = (size_t)lane * 8;
    int e = beg;
    for (; e + 8 <= end; e += 8) {
        int sidx[8];
        #pragma unroll
        for (int j = 0; j < 8; j++) sidx[j] = esrc[e + j];
        uint4 v[8];
        #pragma unroll
        for (int j = 0; j < 8; j++)
            v[j] = *(const uint4*)(xb + (size_t)sidx[j] * HIDC + loff);
        #pragma unroll
        for (int j = 0; j < 8; j++) {
            a[0] += blo(v[j].x); a[1] += bhi(v[j].x);
            a[2] += blo(v[j].y); a[3] += bhi(v[j].y);
            a[4] += blo(v[j].z); a[5] += bhi(v[j].z);
            a[6] += blo(v[j].w); a[7] += bhi(v[j].w);
        }
    }
    if (e + 4 <= end) {
        int sidx[4];
        #pragma unroll
        for (int j = 0; j < 4; j++) sidx[j] = esrc[e + j];
        uint4 v[4];
        #pragma unroll
        for (int j = 0; j < 4; j++)
            v[j] = *(const uint4*)(xb + (size_t)sidx[j] * HIDC + loff);
        #pragma unroll
        for (int j = 0; j < 4; j++) {
            a[0] += blo(v[j].x); a[1] += bhi(v[j].x);
            a[2] += blo(v[j].y); a[3] += bhi(v[j].y);
            a[4] += blo(v[j].z); a[5] += bhi(v[j].z);
            a[6] += blo(v[j].w); a[7] += bhi(v[j].w);
        }
        e += 4;
    }
    for (; e < end; e++) {
        uint4 v = *(const uint4*)(xb + (size_t)esrc[e] * HIDC + loff);
        a[0] += blo(v.x); a[1] += bhi(v.x);
        a[2] += blo(v.y); a[3] += bhi(v.y);
        a[4] += blo(v.z); a[5] += bhi(v.z);
        a[6] += blo(v.w); a[7] += bhi(v.w);
    }
    float w = 1.0f / (float)max(end - beg, 1);
    uint4 o;
    o.x = pkb(a[0] * w, a[1] * w);
    o.y = pkb(a[2] * w, a[3] * w);
    o.z = pkb(a[4] * w, a[5] * w);
    o.w = pkb(a[6] * w, a[7] * w);
    *(uint4*)(cb + (size_t)node * HIDC + loff) = o;
}

// ---------------- MFMA GEMM + fused epilogue ----------------
template<int KSTEPS, bool AF32, bool FULL>
__global__ __launch_bounds__(256) void k_gemm(const void* __restrict__ a0v,
        const unsigned short* __restrict__ a1, int astride, int ksplit,
        const unsigned short* __restrict__ wsw, const float* __restrict__ bias,
        unsigned short* __restrict__ xb) {
    __shared__ unsigned short As[4 * 64 * 8];   // 4 KB, fragment order
    __shared__ float rs[64];
    int tid = threadIdx.x;
    int w = tid >> 6;
    int lane = tid & 63;
    int quad = lane >> 4;
    int l15 = lane & 15;
    int row0 = blockIdx.x * 64;

    floatx4 acc[4][4];
    #pragma unroll
    for (int mt = 0; mt < 4; mt++)
        #pragma unroll
        for (int ntl = 0; ntl < 4; ntl++)
            acc[mt][ntl] = (floatx4){0.f, 0.f, 0.f, 0.f};

    int sm = tid >> 2;
    int sq = tid & 3;
    int srow = row0 + sm;
    int soff = ((sm >> 4) * 64 + (sq << 4) + (sm & 15)) * 8;

    for (int ks = 0; ks < KSTEPS; ks++) {
        __syncthreads();
        int k = ks * 32 + sq * 8;
        uint4 av = make_uint4(0, 0, 0, 0);
        if (srow < N_NODESC) {
            if (AF32) {
                const float* p = (const float*)a0v + (size_t)srow * astride + k;
                float4 f0 = *(const float4*)p;
                float4 f1 = *(const float4*)(p + 4);
                av.x = pkb(f0.x, f0.y); av.y = pkb(f0.z, f0.w);
                av.z = pkb(f1.x, f1.y); av.w = pkb(f1.z, f1.w);
            } else {
                const unsigned short* p = (k < ksplit)
                    ? ((const unsigned short*)a0v + (size_t)srow * astride + k)
                    : (a1 + (size_t)srow * astride + (k - ksplit));
                av = *(const uint4*)p;
            }
        }
        *(uint4*)&As[soff] = av;
        __syncthreads();

        short8 afr[4], bfr[4];
        #pragma unroll
        for (int mt = 0; mt < 4; mt++)
            afr[mt] = *(const short8*)&As[(mt * 64 + lane) * 8];
        const unsigned short* wp = wsw + ((size_t)(ks * 16 + w * 4) * 64 + lane) * 8;
        #pragma unroll
        for (int ntl = 0; ntl < 4; ntl++)
            bfr[ntl] = *(const short8*)(wp + ntl * 512);
        #pragma unroll
        for (int mt = 0; mt < 4; mt++)
            #pragma unroll
            for (int ntl = 0; ntl < 4; ntl++)
                acc[mt][ntl] = __builtin_amdgcn_mfma_f32_16x16x32_bf16(
                    afr[mt], bfr[ntl], acc[mt][ntl], 0, 0, 0);
    }

    float bv[4];
    #pragma unroll
    for (int ntl = 0; ntl < 4; ntl++) bv[ntl] = bias[(w * 4 + ntl) * 16 + l15];
    #pragma unroll
    for (int mt = 0; mt < 4; mt++)
        #pragma unroll
        for (int ntl = 0; ntl < 4; ntl++)
            #pragma unroll
            for (int r = 0; r < 4; r++)
                acc[mt][ntl][r] += bv[ntl];

    if (FULL) {
        __syncthreads();
        if (tid < 64) rs[tid] = 0.f;
        __syncthreads();
        #pragma unroll
        for (int mt = 0; mt < 4; mt++) {
            #pragma unroll
            for (int r = 0; r < 4; r++) {
                float p = acc[mt][0][r] * acc[mt][0][r] + acc[mt][1][r] * acc[mt][1][r]
                        + acc[mt][2][r] * acc[mt][2][r] + acc[mt][3][r] * acc[mt][3][r];
                p += __shfl_xor(p, 1);
                p += __shfl_xor(p, 2);
                p += __shfl_xor(p, 4);
                p += __shfl_xor(p, 8);
                if (l15 == 0) atomicAdd(&rs[mt * 16 + quad * 4 + r], p);
            }
        }
        __syncthreads();
        #pragma unroll
        for (int mt = 0; mt < 4; mt++) {
            #pragma unroll
            for (int r = 0; r < 4; r++) {
                int row = row0 + mt * 16 + quad * 4 + r;
                if (row < N_NODESC) {
                    float inv = 1.0f / fmaxf(sqrtf(rs[mt * 16 + quad * 4 + r]), EPSV);
                    #pragma unroll
                    for (int ntl = 0; ntl < 4; ntl++) {
                        int col = (w * 4 + ntl) * 16 + l15;
                        size_t idx = (size_t)row * HIDC + col;
                        float xo = b2f(xb[idx]);
                        float v = fmaxf(acc[mt][ntl][r] * inv, 0.f);
                        xb[idx] = f2b(xo + v);
                    }
                }
            }
        }
    } else {
        #pragma unroll
        for (int mt = 0; mt < 4; mt++) {
            #pragma unroll
            for (int r = 0; r < 4; r++) {
                int row = row0 + mt * 16 + quad * 4 + r;
                if (row < N_NODESC) {
                    #pragma unroll
                    for (int ntl = 0; ntl < 4; ntl++) {
                        int col = (w * 4 + ntl) * 16 + l15;
                        xb[(size_t)row * HIDC + col] = f2b(acc[mt][ntl][r]);
                    }
                }
            }
        }
    }
}

// ---------------- graph mean-pool: 1 block per (graph, 64-col quarter) ----------------
__global__ __launch_bounds__(256) void k_pool(const unsigned short* __restrict__ xb,
        const int* __restrict__ gstart, float* __restrict__ hg) {
    __shared__ float red[256][8];
    int g = blockIdx.x >> 2;
    int cq = blockIdx.x & 3;
    int t = threadIdx.x;
    int cchunk = t & 7;      // 8 chunks of 8 cols
    int rgrp = t >> 3;       // 32 parallel row streams
    int col0 = cq * 64 + cchunk * 8;
    int beg = gstart[g], end = gstart[g + 1];
    float a[8];
    #pragma unroll
    for (int j = 0; j < 8; j++) a[j] = 0.f;
    for (int r = beg + rgrp; r < end; r += 32) {
        uint4 v = *(const uint4*)(xb + (size_t)r * HIDC + col0);
        a[0] += blo(v.x); a[1] += bhi(v.x);
        a[2] += blo(v.y); a[3] += bhi(v.y);
        a[4] += blo(v.z); a[5] += bhi(v.z);
        a[6] += blo(v.w); a[7] += bhi(v.w);
    }
    #pragma unroll
    for (int j = 0; j < 8; j++) red[t][j] = a[j];
    __syncthreads();
    for (int d = 16; d >= 1; d >>= 1) {
        if (rgrp < d) {
            #pragma unroll
            for (int j = 0; j < 8; j++) red[t][j] += red[t + d * 8][j];
        }
        __syncthreads();
    }
    if (rgrp == 0) {
        float inv = 1.0f / (float)max(end - beg, 1);
        #pragma unroll
        for (int j = 0; j < 8; j++)
            hg[g * HIDC + col0 + j] = red[t][j] * inv;
    }
}

// ---------------- readout ----------------
__global__ __launch_bounds__(256) void k_readout(const float* __restrict__ hg,
        const float* __restrict__ ppos, const float* __restrict__ pneg,
        const float* __restrict__ wfc, float* __restrict__ out) {
    __shared__ float red[256];
    __shared__ float ss[10];
    int t = threadIdx.x;
    int g = blockIdx.x;
    float hgv = hg[g * HIDC + t];
    for (int p = 0; p < 10; p++) {
        const float* P = (p < 5) ? (ppos + p * HIDC) : (pneg + (p - 5) * HIDC);
        float d = hgv - P[t];
        red[t] = d * d;
        __syncthreads();
        for (int s2 = 128; s2 > 0; s2 >>= 1) {
            if (t < s2) red[t] += red[t + s2];
            __syncthreads();
        }
        if (t == 0) {
            float dd = red[0];
            ss[p] = logf((dd + 1.0f) / (dd + EPSV));
        }
        __syncthreads();
    }
    if (t == 0) {
        float y = 0.f;
        #pragma unroll
        for (int p = 0; p < 10; p++) y += ss[p] * wfc[p];
        out[g] = 1.0f / (1.0f + expf(-y));
    }
}

extern "C" void kernel_launch(void* const* d_in, const int* in_sizes, int n_in,
                              void* d_out, int out_size, void* d_ws, size_t ws_size,
                              hipStream_t stream) {
    const float* h    = (const float*)d_in[0];
    const int*   src  = (const int*)d_in[1];
    const int*   dst  = (const int*)d_in[2];
    const int*   gid  = (const int*)d_in[3];
    const float* Wemb = (const float*)d_in[4];
    const float* bemb = (const float*)d_in[5];
    const float* Ws   = (const float*)d_in[6];
    const float* bs   = (const float*)d_in[7];
    const float* ppos = (const float*)d_in[8];
    const float* pneg = (const float*)d_in[9];
    const float* wfc  = (const float*)d_in[10];
    float* out = (float*)d_out;

    char* ws = (char*)d_ws;
    size_t off = 0;
    auto alloc = [&](size_t bytes) {
        void* p = ws + off;
        off += (bytes + 255) & ~(size_t)255;
        return p;
    };
    unsigned short* xb  = (unsigned short*)alloc((size_t)N_NODESC * HIDC * 2);
    unsigned short* cb  = (unsigned short*)alloc((size_t)N_NODESC * HIDC * 2);
    unsigned short* wsw = (unsigned short*)alloc((size_t)(IN_DIMC * HIDC + N_LAYERSC * 2 * HIDC * HIDC) * 2);
    int*   deg    = (int*)alloc((size_t)N_NODESC * 4);
    int*   offs   = (int*)alloc((size_t)(N_NODESC + 1) * 4);
    int*   cursor = (int*)alloc((size_t)N_NODESC * 4);
    int*   esrc   = (int*)alloc((size_t)N_EDGESC * 4);
    int*   bsum   = (int*)alloc((size_t)SCAN_BLK * 4);
    int*   boff   = (int*)alloc((size_t)SCAN_BLK * 4);
    int*   gdeg   = (int*)alloc((size_t)N_GRAPHSC * 4);
    int*   gstart = (int*)alloc((size_t)(N_GRAPHSC + 1) * 4);
    float* hg     = (float*)alloc((size_t)N_GRAPHSC * HIDC * 4);
    (void)ws_size; (void)in_sizes; (void)n_in; (void)out_size;

    hipMemsetAsync(deg, 0, (size_t)N_NODESC * 4, stream);
    hipMemsetAsync(gdeg, 0, (size_t)N_GRAPHSC * 4, stream);

    const int WTOT = IN_DIMC * HIDC + N_LAYERSC * 2 * HIDC * HIDC; // 557056
    k_wconv<<<(WTOT + 255) / 256, 256, 0, stream>>>(Wemb, Ws, wsw);
    k_count<<<(N_EDGESC + 255) / 256, 256, 0, stream>>>(dst, deg);
    k_gcount<<<(N_NODESC + 255) / 256, 256, 0, stream>>>(gid, gdeg);
    k_gprefix<<<1, 64, 0, stream>>>(gdeg, gstart);
    k_scanA<<<SCAN_BLK, 256, 0, stream>>>(deg, bsum);
    k_scanB<<<1, 256, 0, stream>>>(bsum, boff);
    k_scanC<<<SCAN_BLK, 256, 0, stream>>>(deg, boff, offs, cursor);
    k_scatter<<<(N_EDGESC + 255) / 256, 256, 0, stream>>>(src, dst, cursor, esrc);

    const int GBLK = (N_NODESC + 63) / 64; // 782
    k_gemm<4, true, false><<<GBLK, 256, 0, stream>>>(
        h, nullptr, IN_DIMC, IN_DIMC, wsw, bemb, xb);

    for (int l = 0; l < N_LAYERSC; l++) {
        k_aggregate<<<(N_NODESC * 32 + 255) / 256, 256, 0, stream>>>(xb, offs, esrc, cb);
        k_gemm<16, false, true><<<GBLK, 256, 0, stream>>>(
            xb, cb, HIDC, HIDC,
            wsw + IN_DIMC * HIDC + (size_t)l * 2 * HIDC * HIDC,
            bs + (size_t)l * HIDC, xb);
    }
    k_pool<<<N_GRAPHSC * 4, 256, 0, stream>>>(xb, gstart, hg);
    k_readout<<<N_GRAPHSC, 256, 0, stream>>>(hg, ppos, pneg, wfc, out);
}

// Round 5
// 673.550 us; speedup vs baseline: 1.3399x; 1.3399x over previous
//
#include <hip/hip_runtime.h>
#include <math.h>

#define N_NODESC 50000
#define N_EDGESC 800000
#define N_GRAPHSC 64
#define IN_DIMC 128
#define HIDC 256
#define N_LAYERSC 4
#define EPSV 1e-12f

#define SCAN_BLK 196  // ceil(50000/256)

typedef __attribute__((ext_vector_type(8))) short short8;
typedef __attribute__((ext_vector_type(4))) float floatx4;

__device__ __forceinline__ unsigned short f2b(float f) {
    union { float f; unsigned u; } v; v.f = f;
    unsigned r = v.u + 0x7FFFu + ((v.u >> 16) & 1u);
    return (unsigned short)(r >> 16);
}
__device__ __forceinline__ float blo(unsigned u) { return __uint_as_float(u << 16); }
__device__ __forceinline__ float bhi(unsigned u) { return __uint_as_float(u & 0xFFFF0000u); }
__device__ __forceinline__ unsigned pkb(float a, float b) {
    return (unsigned)f2b(a) | ((unsigned)f2b(b) << 16);
}
__device__ __forceinline__ float b2f(unsigned short s) {
    return __uint_as_float((unsigned)s << 16);
}

// ---------------- degree count ----------------
__global__ void k_count(const int* __restrict__ dst, int* __restrict__ deg) {
    int e = blockIdx.x * blockDim.x + threadIdx.x;
    if (e < N_EDGESC) atomicAdd(&deg[dst[e]], 1);
}

// ---------------- graph boundaries via binary search (gid sorted) ----------------
__global__ __launch_bounds__(128) void k_gbounds(const int* __restrict__ gid,
        int* __restrict__ gstart) {
    int g = threadIdx.x;
    if (g > N_GRAPHSC) return;
    int lo = 0, hi = N_NODESC;
    while (lo < hi) {
        int mid = (lo + hi) >> 1;
        if (gid[mid] < g) lo = mid + 1; else hi = mid;
    }
    gstart[g] = lo;
}

// ---------------- hierarchical scan: A = block sums ----------------
__global__ __launch_bounds__(256) void k_scanA(const int* __restrict__ deg,
        int* __restrict__ bsum) {
    __shared__ int s[256];
    int t = threadIdx.x;
    int i = blockIdx.x * 256 + t;
    s[t] = (i < N_NODESC) ? deg[i] : 0;
    __syncthreads();
    for (int d = 128; d > 0; d >>= 1) {
        if (t < d) s[t] += s[t + d];
        __syncthreads();
    }
    if (t == 0) bsum[blockIdx.x] = s[0];
}

// ---------------- B = exclusive scan of block sums ----------------
__global__ __launch_bounds__(256) void k_scanB(const int* __restrict__ bsum,
        int* __restrict__ boff) {
    __shared__ int s[256];
    int t = threadIdx.x;
    int v = (t < SCAN_BLK) ? bsum[t] : 0;
    s[t] = v;
    __syncthreads();
    for (int d = 1; d < 256; d <<= 1) {
        int u = (t >= d) ? s[t - d] : 0;
        __syncthreads();
        s[t] += u;
        __syncthreads();
    }
    if (t < SCAN_BLK) boff[t] = s[t] - v;
}

// ---------------- C = per-block exclusive scan + base ----------------
__global__ __launch_bounds__(256) void k_scanC(const int* __restrict__ deg,
        const int* __restrict__ boff, int* __restrict__ offs, int* __restrict__ cursor) {
    __shared__ int s[256];
    int t = threadIdx.x;
    int i = blockIdx.x * 256 + t;
    int v = (i < N_NODESC) ? deg[i] : 0;
    s[t] = v;
    __syncthreads();
    for (int d = 1; d < 256; d <<= 1) {
        int u = (t >= d) ? s[t - d] : 0;
        __syncthreads();
        s[t] += u;
        __syncthreads();
    }
    int excl = s[t] - v + boff[blockIdx.x];
    if (i < N_NODESC) {
        offs[i] = excl;
        cursor[i] = excl;
        if (i == N_NODESC - 1) offs[N_NODESC] = excl + v;
    }
}

// ---------------- scatter edges into CSR buckets ----------------
__global__ void k_scatter(const int* __restrict__ src, const int* __restrict__ dst,
        int* __restrict__ cursor, int* __restrict__ esrc) {
    int e = blockIdx.x * blockDim.x + threadIdx.x;
    if (e < N_EDGESC) {
        int d = dst[e];
        int pos = atomicAdd(&cursor[d], 1);
        esrc[pos] = src[e];
    }
}

// ---------------- weight convert + swizzle to MFMA B-fragment order ----------------
__global__ __launch_bounds__(256) void k_wconv(const float* __restrict__ Wemb,
        const float* __restrict__ Ws, unsigned short* __restrict__ wsw) {
    int idx = blockIdx.x * 256 + threadIdx.x;
    const int EMB = IN_DIMC * HIDC;           // 32768
    const int LYR = 2 * HIDC * HIDC;          // 131072
    if (idx >= EMB + N_LAYERSC * LYR) return;
    float val; int k, n; unsigned short* basep;
    if (idx < EMB) {
        k = idx >> 8; n = idx & 255;
        val = Wemb[idx];
        basep = wsw;
    } else {
        int r = idx - EMB;
        int l = r >> 17;
        int r2 = r & (LYR - 1);
        k = r2 >> 8; n = r2 & 255;
        val = Ws[r];
        basep = wsw + EMB + l * LYR;
    }
    int off = (((k >> 5) * 16 + (n >> 4)) * 64 + ((((k >> 3) & 3) << 4) | (n & 15))) * 8 + (k & 7);
    basep[off] = f2b(val);
}

// ---------------- per-node mean aggregation (32 lanes/node, uint4/lane, 8-deep MLP) ----------------
__global__ __launch_bounds__(256) void k_aggregate(const unsigned short* __restrict__ xb,
        const int* __restrict__ offs, const int* __restrict__ esrc,
        unsigned short* __restrict__ cb) {
    int gidx = blockIdx.x * 256 + threadIdx.x;
    int node = gidx >> 5;
    int lane = threadIdx.x & 31;
    if (node >= N_NODESC) return;
    int beg = offs[node], end = offs[node + 1];
    float a[8];
    #pragma unroll
    for (int j = 0; j < 8; j++) a[j] = 0.f;
    size_t loff = (size_t)lane * 8;
    int e = beg;
    for (; e + 8 <= end; e += 8) {
        int sidx[8];
        #pragma unroll
        for (int j = 0; j < 8; j++) sidx[j] = esrc[e + j];
        uint4 v[8];
        #pragma unroll
        for (int j = 0; j < 8; j++)
            v[j] = *(const uint4*)(xb + (size_t)sidx[j] * HIDC + loff);
        #pragma unroll
        for (int j = 0; j < 8; j++) {
            a[0] += blo(v[j].x); a[1] += bhi(v[j].x);
            a[2] += blo(v[j].y); a[3] += bhi(v[j].y);
            a[4] += blo(v[j].z); a[5] += bhi(v[j].z);
            a[6] += blo(v[j].w); a[7] += bhi(v[j].w);
        }
    }
    if (e + 4 <= end) {
        int sidx[4];
        #pragma unroll
        for (int j = 0; j < 4; j++) sidx[j] = esrc[e + j];
        uint4 v[4];
        #pragma unroll
        for (int j = 0; j < 4; j++)
            v[j] = *(const uint4*)(xb + (size_t)sidx[j] * HIDC + loff);
        #pragma unroll
        for (int j = 0; j < 4; j++) {
            a[0] += blo(v[j].x); a[1] += bhi(v[j].x);
            a[2] += blo(v[j].y); a[3] += bhi(v[j].y);
            a[4] += blo(v[j].z); a[5] += bhi(v[j].z);
            a[6] += blo(v[j].w); a[7] += bhi(v[j].w);
        }
        e += 4;
    }
    for (; e < end; e++) {
        uint4 v = *(const uint4*)(xb + (size_t)esrc[e] * HIDC + loff);
        a[0] += blo(v.x); a[1] += bhi(v.x);
        a[2] += blo(v.y); a[3] += bhi(v.y);
        a[4] += blo(v.z); a[5] += bhi(v.z);
        a[6] += blo(v.w); a[7] += bhi(v.w);
    }
    float w = 1.0f / (float)max(end - beg, 1);
    uint4 o;
    o.x = pkb(a[0] * w, a[1] * w);
    o.y = pkb(a[2] * w, a[3] * w);
    o.z = pkb(a[4] * w, a[5] * w);
    o.w = pkb(a[6] * w, a[7] * w);
    *(uint4*)(cb + (size_t)node * HIDC + loff) = o;
}

// ---------------- MFMA GEMM + fused epilogue ----------------
template<int KSTEPS, bool AF32, bool FULL>
__global__ __launch_bounds__(256) void k_gemm(const void* __restrict__ a0v,
        const unsigned short* __restrict__ a1, int astride, int ksplit,
        const unsigned short* __restrict__ wsw, const float* __restrict__ bias,
        unsigned short* __restrict__ xb) {
    __shared__ unsigned short As[4 * 64 * 8];   // 4 KB, fragment order
    __shared__ float rs[64];
    int tid = threadIdx.x;
    int w = tid >> 6;
    int lane = tid & 63;
    int quad = lane >> 4;
    int l15 = lane & 15;
    int row0 = blockIdx.x * 64;

    floatx4 acc[4][4];
    #pragma unroll
    for (int mt = 0; mt < 4; mt++)
        #pragma unroll
        for (int ntl = 0; ntl < 4; ntl++)
            acc[mt][ntl] = (floatx4){0.f, 0.f, 0.f, 0.f};

    int sm = tid >> 2;
    int sq = tid & 3;
    int srow = row0 + sm;
    int soff = ((sm >> 4) * 64 + (sq << 4) + (sm & 15)) * 8;

    for (int ks = 0; ks < KSTEPS; ks++) {
        __syncthreads();
        int k = ks * 32 + sq * 8;
        uint4 av = make_uint4(0, 0, 0, 0);
        if (srow < N_NODESC) {
            if (AF32) {
                const float* p = (const float*)a0v + (size_t)srow * astride + k;
                float4 f0 = *(const float4*)p;
                float4 f1 = *(const float4*)(p + 4);
                av.x = pkb(f0.x, f0.y); av.y = pkb(f0.z, f0.w);
                av.z = pkb(f1.x, f1.y); av.w = pkb(f1.z, f1.w);
            } else {
                const unsigned short* p = (k < ksplit)
                    ? ((const unsigned short*)a0v + (size_t)srow * astride + k)
                    : (a1 + (size_t)srow * astride + (k - ksplit));
                av = *(const uint4*)p;
            }
        }
        *(uint4*)&As[soff] = av;
        __syncthreads();

        short8 afr[4], bfr[4];
        #pragma unroll
        for (int mt = 0; mt < 4; mt++)
            afr[mt] = *(const short8*)&As[(mt * 64 + lane) * 8];
        const unsigned short* wp = wsw + ((size_t)(ks * 16 + w * 4) * 64 + lane) * 8;
        #pragma unroll
        for (int ntl = 0; ntl < 4; ntl++)
            bfr[ntl] = *(const short8*)(wp + ntl * 512);
        #pragma unroll
        for (int mt = 0; mt < 4; mt++)
            #pragma unroll
            for (int ntl = 0; ntl < 4; ntl++)
                acc[mt][ntl] = __builtin_amdgcn_mfma_f32_16x16x32_bf16(
                    afr[mt], bfr[ntl], acc[mt][ntl], 0, 0, 0);
    }

    float bv[4];
    #pragma unroll
    for (int ntl = 0; ntl < 4; ntl++) bv[ntl] = bias[(w * 4 + ntl) * 16 + l15];
    #pragma unroll
    for (int mt = 0; mt < 4; mt++)
        #pragma unroll
        for (int ntl = 0; ntl < 4; ntl++)
            #pragma unroll
            for (int r = 0; r < 4; r++)
                acc[mt][ntl][r] += bv[ntl];

    if (FULL) {
        __syncthreads();
        if (tid < 64) rs[tid] = 0.f;
        __syncthreads();
        #pragma unroll
        for (int mt = 0; mt < 4; mt++) {
            #pragma unroll
            for (int r = 0; r < 4; r++) {
                float p = acc[mt][0][r] * acc[mt][0][r] + acc[mt][1][r] * acc[mt][1][r]
                        + acc[mt][2][r] * acc[mt][2][r] + acc[mt][3][r] * acc[mt][3][r];
                p += __shfl_xor(p, 1);
                p += __shfl_xor(p, 2);
                p += __shfl_xor(p, 4);
                p += __shfl_xor(p, 8);
                if (l15 == 0) atomicAdd(&rs[mt * 16 + quad * 4 + r], p);
            }
        }
        __syncthreads();
        #pragma unroll
        for (int mt = 0; mt < 4; mt++) {
            #pragma unroll
            for (int r = 0; r < 4; r++) {
                int row = row0 + mt * 16 + quad * 4 + r;
                if (row < N_NODESC) {
                    float inv = 1.0f / fmaxf(sqrtf(rs[mt * 16 + quad * 4 + r]), EPSV);
                    #pragma unroll
                    for (int ntl = 0; ntl < 4; ntl++) {
                        int col = (w * 4 + ntl) * 16 + l15;
                        size_t idx = (size_t)row * HIDC + col;
                        float xo = b2f(xb[idx]);
                        float v = fmaxf(acc[mt][ntl][r] * inv, 0.f);
                        xb[idx] = f2b(xo + v);
                    }
                }
            }
        }
    } else {
        #pragma unroll
        for (int mt = 0; mt < 4; mt++) {
            #pragma unroll
            for (int r = 0; r < 4; r++) {
                int row = row0 + mt * 16 + quad * 4 + r;
                if (row < N_NODESC) {
                    #pragma unroll
                    for (int ntl = 0; ntl < 4; ntl++) {
                        int col = (w * 4 + ntl) * 16 + l15;
                        xb[(size_t)row * HIDC + col] = f2b(acc[mt][ntl][r]);
                    }
                }
            }
        }
    }
}

// ---------------- graph mean-pool: 1 block per (graph, 64-col quarter) ----------------
__global__ __launch_bounds__(256) void k_pool(const unsigned short* __restrict__ xb,
        const int* __restrict__ gstart, float* __restrict__ hg) {
    __shared__ float red[256][8];
    int g = blockIdx.x >> 2;
    int cq = blockIdx.x & 3;
    int t = threadIdx.x;
    int cchunk = t & 7;      // 8 chunks of 8 cols
    int rgrp = t >> 3;       // 32 parallel row streams
    int col0 = cq * 64 + cchunk * 8;
    int beg = gstart[g], end = gstart[g + 1];
    float a[8];
    #pragma unroll
    for (int j = 0; j < 8; j++) a[j] = 0.f;
    for (int r = beg + rgrp; r < end; r += 32) {
        uint4 v = *(const uint4*)(xb + (size_t)r * HIDC + col0);
        a[0] += blo(v.x); a[1] += bhi(v.x);
        a[2] += blo(v.y); a[3] += bhi(v.y);
        a[4] += blo(v.z); a[5] += bhi(v.z);
        a[6] += blo(v.w); a[7] += bhi(v.w);
    }
    #pragma unroll
    for (int j = 0; j < 8; j++) red[t][j] = a[j];
    __syncthreads();
    for (int d = 16; d >= 1; d >>= 1) {
        if (rgrp < d) {
            #pragma unroll
            for (int j = 0; j < 8; j++) red[t][j] += red[t + d * 8][j];
        }
        __syncthreads();
    }
    if (rgrp == 0) {
        float inv = 1.0f / (float)max(end - beg, 1);
        #pragma unroll
        for (int j = 0; j < 8; j++)
            hg[g * HIDC + col0 + j] = red[t][j] * inv;
    }
}

// ---------------- readout ----------------
__global__ __launch_bounds__(256) void k_readout(const float* __restrict__ hg,
        const float* __restrict__ ppos, const float* __restrict__ pneg,
        const float* __restrict__ wfc, float* __restrict__ out) {
    __shared__ float red[256];
    __shared__ float ss[10];
    int t = threadIdx.x;
    int g = blockIdx.x;
    float hgv = hg[g * HIDC + t];
    for (int p = 0; p < 10; p++) {
        const float* P = (p < 5) ? (ppos + p * HIDC) : (pneg + (p - 5) * HIDC);
        float d = hgv - P[t];
        red[t] = d * d;
        __syncthreads();
        for (int s2 = 128; s2 > 0; s2 >>= 1) {
            if (t < s2) red[t] += red[t + s2];
            __syncthreads();
        }
        if (t == 0) {
            float dd = red[0];
            ss[p] = logf((dd + 1.0f) / (dd + EPSV));
        }
        __syncthreads();
    }
    if (t == 0) {
        float y = 0.f;
        #pragma unroll
        for (int p = 0; p < 10; p++) y += ss[p] * wfc[p];
        out[g] = 1.0f / (1.0f + expf(-y));
    }
}

extern "C" void kernel_launch(void* const* d_in, const int* in_sizes, int n_in,
                              void* d_out, int out_size, void* d_ws, size_t ws_size,
                              hipStream_t stream) {
    const float* h    = (const float*)d_in[0];
    const int*   src  = (const int*)d_in[1];
    const int*   dst  = (const int*)d_in[2];
    const int*   gid  = (const int*)d_in[3];
    const float* Wemb = (const float*)d_in[4];
    const float* bemb = (const float*)d_in[5];
    const float* Ws   = (const float*)d_in[6];
    const float* bs   = (const float*)d_in[7];
    const float* ppos = (const float*)d_in[8];
    const float* pneg = (const float*)d_in[9];
    const float* wfc  = (const float*)d_in[10];
    float* out = (float*)d_out;

    char* ws = (char*)d_ws;
    size_t off = 0;
    auto alloc = [&](size_t bytes) {
        void* p = ws + off;
        off += (bytes + 255) & ~(size_t)255;
        return p;
    };
    unsigned short* xb  = (unsigned short*)alloc((size_t)N_NODESC * HIDC * 2);
    unsigned short* cb  = (unsigned short*)alloc((size_t)N_NODESC * HIDC * 2);
    unsigned short* wsw = (unsigned short*)alloc((size_t)(IN_DIMC * HIDC + N_LAYERSC * 2 * HIDC * HIDC) * 2);
    int*   deg    = (int*)alloc((size_t)N_NODESC * 4);
    int*   offs   = (int*)alloc((size_t)(N_NODESC + 1) * 4);
    int*   cursor = (int*)alloc((size_t)N_NODESC * 4);
    int*   esrc   = (int*)alloc((size_t)N_EDGESC * 4);
    int*   bsum   = (int*)alloc((size_t)SCAN_BLK * 4);
    int*   boff   = (int*)alloc((size_t)SCAN_BLK * 4);
    int*   gstart = (int*)alloc((size_t)(N_GRAPHSC + 1) * 4);
    float* hg     = (float*)alloc((size_t)N_GRAPHSC * HIDC * 4);
    (void)ws_size; (void)in_sizes; (void)n_in; (void)out_size;

    hipMemsetAsync(deg, 0, (size_t)N_NODESC * 4, stream);

    const int WTOT = IN_DIMC * HIDC + N_LAYERSC * 2 * HIDC * HIDC; // 557056
    k_wconv<<<(WTOT + 255) / 256, 256, 0, stream>>>(Wemb, Ws, wsw);
    k_count<<<(N_EDGESC + 255) / 256, 256, 0, stream>>>(dst, deg);
    k_gbounds<<<1, 128, 0, stream>>>(gid, gstart);
    k_scanA<<<SCAN_BLK, 256, 0, stream>>>(deg, bsum);
    k_scanB<<<1, 256, 0, stream>>>(bsum, boff);
    k_scanC<<<SCAN_BLK, 256, 0, stream>>>(deg, boff, offs, cursor);
    k_scatter<<<(N_EDGESC + 255) / 256, 256, 0, stream>>>(src, dst, cursor, esrc);

    const int GBLK = (N_NODESC + 63) / 64; // 782
    k_gemm<4, true, false><<<GBLK, 256, 0, stream>>>(
        h, nullptr, IN_DIMC, IN_DIMC, wsw, bemb, xb);

    for (int l = 0; l < N_LAYERSC; l++) {
        k_aggregate<<<(N_NODESC * 32 + 255) / 256, 256, 0, stream>>>(xb, offs, esrc, cb);
        k_gemm<16, false, true><<<GBLK, 256, 0, stream>>>(
            xb, cb, HIDC, HIDC,
            wsw + IN_DIMC * HIDC + (size_t)l * 2 * HIDC * HIDC,
            bs + (size_t)l * HIDC, xb);
    }
    k_pool<<<N_GRAPHSC * 4, 256, 0, stream>>>(xb, gstart, hg);
    k_readout<<<N_GRAPHSC, 256, 0, stream>>>(hg, ppos, pneg, wfc, out);
}